// Round 5
// baseline (291.926 us; speedup 1.0000x reference)
//
#include <hip/hip_runtime.h>
#include <hip/hip_bf16.h>
#include <cstdint>
#include <cstddef>

#define NPTS 16000
#define KNB  16
#define CDIM 384
#define NH   6
#define HDIM 64
#define T2C  49
#define NQKV 1152            // 3*384 fused q,k,v output cols
#define NL3T 147             // 49*3 table rows
#define DSTR 882             // 147*6 : per-point dq/dk row stride (elems)

static constexpr float WIN    = 6.0f;
static constexpr float QUANT  = 0.24f;
static constexpr float QSCALE = 0.125f; // 64^-0.5

typedef __attribute__((ext_vector_type(8))) short short8;
typedef __attribute__((ext_vector_type(4))) float floatx4;
typedef __attribute__((ext_vector_type(4))) unsigned short ushort4v;

__device__ inline unsigned short f2bf(float x) {
    unsigned int u = __float_as_uint(x);
    unsigned int r = (u + 0x7fffu + ((u >> 16) & 1u)) >> 16;
    return (unsigned short)r;
}
__device__ inline float bf2f(unsigned short b) {
    return __uint_as_float(((unsigned int)b) << 16);
}

// ---------------------------------------------------------------- min reduce
__global__ void init_min_kernel(unsigned int* minbits) {
    if (threadIdx.x < 3) minbits[threadIdx.x] = 0x7f800000u; // +inf
}

__global__ void min_kernel(const float* __restrict__ xyz,
                           unsigned int* __restrict__ minbits) {
    float m0 = INFINITY, m1 = INFINITY, m2 = INFINITY;
    for (int i = blockIdx.x * blockDim.x + threadIdx.x; i < NPTS;
         i += gridDim.x * blockDim.x) {
        m0 = fminf(m0, xyz[i * 3 + 0]);
        m1 = fminf(m1, xyz[i * 3 + 1]);
        m2 = fminf(m2, xyz[i * 3 + 2]);
    }
#pragma unroll
    for (int off = 1; off < 64; off <<= 1) {
        m0 = fminf(m0, __shfl_xor(m0, off, 64));
        m1 = fminf(m1, __shfl_xor(m1, off, 64));
        m2 = fminf(m2, __shfl_xor(m2, off, 64));
    }
    if ((threadIdx.x & 63) == 0) {
        atomicMin(&minbits[0], __float_as_uint(m0)); // xyz >= 0
        atomicMin(&minbits[1], __float_as_uint(m1));
        atomicMin(&minbits[2], __float_as_uint(m2));
    }
}

// ------------------------------------------------------------- quantize xyz
__global__ void xq_kernel(const float* __restrict__ xyz,
                          const int* __restrict__ sort_idx,
                          const unsigned int* __restrict__ minbits,
                          int* __restrict__ xq) {
    int n = blockIdx.x * blockDim.x + threadIdx.x;
    if (n >= NPTS) return;
    int orig = sort_idx[n];
#pragma unroll
    for (int t = 0; t < 3; ++t) {
        float mn = __uint_as_float(minbits[t]);
        float v  = xyz[orig * 3 + t] - mn;   // >= 0
        float md = fmodf(v, WIN);            // == np.mod for non-negative
        float q  = floorf(md / QUANT);
        xq[n * 3 + t] = (int)q;
    }
}

// ----------------------------------------------- pack (key, rel0..2) per pair
__global__ void relpack_kernel(const int* __restrict__ idx1,
                               const int* __restrict__ xq,
                               unsigned int* __restrict__ pairs) {
    int m = blockIdx.x * blockDim.x + threadIdx.x;
    if (m >= NPTS * KNB) return;
    int n = m >> 4;
    int key = idx1[m];
    int r0 = xq[n * 3 + 0] - xq[key * 3 + 0] + 24; r0 = min(max(r0, 0), T2C - 1);
    int r1 = xq[n * 3 + 1] - xq[key * 3 + 1] + 24; r1 = min(max(r1, 0), T2C - 1);
    int r2 = xq[n * 3 + 2] - xq[key * 3 + 2] + 24; r2 = min(max(r2, 0), T2C - 1);
    pairs[m] = (unsigned)key | ((unsigned)r0 << 14) | ((unsigned)r1 << 20) |
               ((unsigned)r2 << 26);
}

// ------------------------------------------------- gather+convert feats->bf16
__global__ void gather_bf16_kernel(const float* __restrict__ feats,
                                   const int* __restrict__ sortix,
                                   unsigned short* __restrict__ out) {
    int i = blockIdx.x * blockDim.x + threadIdx.x; // group of 4 elements
    if (i >= NPTS * CDIM / 4) return;
    int n  = i / (CDIM / 4);
    int c4 = (i % (CDIM / 4)) * 4;
    const float4 v = *(const float4*)&feats[(size_t)sortix[n] * CDIM + c4];
    ushort4v o;
    o.x = f2bf(v.x); o.y = f2bf(v.y); o.z = f2bf(v.z); o.w = f2bf(v.w);
    *(ushort4v*)&out[(size_t)n * CDIM + c4] = o;
}

// --------------------------------------------- pack W(q|k|v|p) -> bf16, biases
__global__ void pack_w_kernel(const float* __restrict__ Wq,
                              const float* __restrict__ Wk,
                              const float* __restrict__ Wv,
                              const float* __restrict__ Wp,
                              const float* __restrict__ bq,
                              const float* __restrict__ bk,
                              const float* __restrict__ bv,
                              const float* __restrict__ bp,
                              unsigned short* __restrict__ Wcat,
                              float* __restrict__ bcat) {
    int i = blockIdx.x * blockDim.x + threadIdx.x;
    if (i < NQKV + CDIM)
        bcat[i] = (i < 384) ? bq[i] : (i < 768) ? bk[i - 384]
                : (i < 1152) ? bv[i - 768] : bp[i - 1152];
    if (i >= (NQKV + CDIM) * CDIM) return;
    int j = i / CDIM, k = i % CDIM;
    float v = (j < 384)  ? Wq[j * CDIM + k]
            : (j < 768)  ? Wk[(j - 384) * CDIM + k]
            : (j < 1152) ? Wv[(j - 768) * CDIM + k]
                         : Wp[(j - 1152) * CDIM + k];
    Wcat[i] = f2bf(v);
}

// ----------------------------------------------------------- Tv table -> bf16
__global__ void tvpack_kernel(const float* __restrict__ Tv,
                              unsigned short* __restrict__ Tvbf) {
    int i = blockIdx.x * blockDim.x + threadIdx.x;
    if (i < NL3T * NH * HDIM) Tvbf[i] = f2bf(Tv[i]);
}

// ------------------------------------------------------ fused bf16 MFMA GEMM
// mode 0: A=featsbf [16000x384], W rows 0..1151  -> qbf (bf16,*SCALE), kh, vh
// mode 1: A=xb      [16000x384], W rows 1152..   -> outf (f32 + bias)
__global__ __launch_bounds__(256) void gemm_fused(
    const unsigned short* __restrict__ Abf,
    const unsigned short* __restrict__ Wrows,   // pre-offset
    const float* __restrict__ bias,             // pre-offset
    int mode,
    unsigned short* __restrict__ qb, unsigned short* __restrict__ kb,
    unsigned short* __restrict__ vb, float* __restrict__ outf) {
    __shared__ unsigned short As[128 * 64];
    __shared__ unsigned short Bs[128 * 64];
    const int tid  = threadIdx.x;
    const int lane = tid & 63;
    const int w    = tid >> 6;
    const int wm   = w >> 1, wn = w & 1;
    const int m0   = blockIdx.x * 128;
    const int jn0  = blockIdx.y * 128;

    floatx4 acc[4][4];
#pragma unroll
    for (int i = 0; i < 4; ++i)
#pragma unroll
        for (int j = 0; j < 4; ++j) acc[i][j] = (floatx4)0.0f;

    for (int kt = 0; kt < 6; ++kt) {
        const int k0 = kt * 64;
#pragma unroll
        for (int q = 0; q < 4; ++q) {
            const int s    = w * 4 + q;            // 1KB segment id
            const int row  = s * 8 + (lane >> 3);
            const int col  = (lane & 7) * 8;
            const unsigned short* ga = Abf   + (size_t)(m0  + row) * CDIM + k0 + col;
            const unsigned short* gb = Wrows + (size_t)(jn0 + row) * CDIM + k0 + col;
            __builtin_amdgcn_global_load_lds(
                (const __attribute__((address_space(1))) void*)ga,
                (__attribute__((address_space(3))) void*)&As[s * 512], 16, 0, 0);
            __builtin_amdgcn_global_load_lds(
                (const __attribute__((address_space(1))) void*)gb,
                (__attribute__((address_space(3))) void*)&Bs[s * 512], 16, 0, 0);
        }
        __syncthreads();
#pragma unroll
        for (int ks = 0; ks < 2; ++ks) {
            short8 a[4], b[4];
#pragma unroll
            for (int mi = 0; mi < 4; ++mi) {
                int row = wm * 64 + mi * 16 + (lane & 15);
                a[mi] = *(const short8*)&As[row * 64 + ks * 32 + (lane >> 4) * 8];
            }
#pragma unroll
            for (int ni = 0; ni < 4; ++ni) {
                int jr = wn * 64 + ni * 16 + (lane & 15);
                b[ni] = *(const short8*)&Bs[jr * 64 + ks * 32 + (lane >> 4) * 8];
            }
#pragma unroll
            for (int mi = 0; mi < 4; ++mi)
#pragma unroll
                for (int ni = 0; ni < 4; ++ni)
                    acc[mi][ni] = __builtin_amdgcn_mfma_f32_16x16x32_bf16(
                        a[mi], b[ni], acc[mi][ni], 0, 0, 0);
        }
        __syncthreads();
    }

#pragma unroll
    for (int mi = 0; mi < 4; ++mi)
#pragma unroll
        for (int ni = 0; ni < 4; ++ni) {
            int j = jn0 + wn * 64 + ni * 16 + (lane & 15);
            float bsv = bias[j];
            if (mode == 0) {
                int which = j / CDIM;
                int c = j - which * CDIM;
                int h = c >> 6, d = c & 63;
#pragma unroll
                for (int r = 0; r < 4; ++r) {
                    int n = m0 + wm * 64 + mi * 16 + (lane >> 4) * 4 + r;
                    float val = acc[mi][ni][r] + bsv;
                    size_t o = ((size_t)h * NPTS + n) * HDIM + d;
                    if (which == 0)      qb[o] = f2bf(val * QSCALE);
                    else if (which == 1) kb[o] = f2bf(val);
                    else                 vb[o] = f2bf(val);
                }
            } else {
#pragma unroll
                for (int r = 0; r < 4; ++r) {
                    int n = m0 + wm * 64 + mi * 16 + (lane >> 4) * 4 + r;
                    outf[(size_t)n * CDIM + j] = acc[mi][ni][r] + bsv;
                }
            }
        }
}

// ----------------------------------- dq/dk table-dot GEMM  [N x 64]x[64 x 147]
// X[n][j][h] (bf16) = A[h][n][:] . T[(j*6+h)*64 + :]   for j < 147
__global__ __launch_bounds__(256) void dqdk_kernel(
    const unsigned short* __restrict__ qbf, const unsigned short* __restrict__ kh,
    const float* __restrict__ Tq, const float* __restrict__ Tk,
    unsigned short* __restrict__ dq2, unsigned short* __restrict__ dk2) {
    const int h   = blockIdx.y;
    const bool isk = blockIdx.z != 0;
    const unsigned short* A = isk ? kh : qbf;
    const float* T          = isk ? Tk : Tq;
    unsigned short* X       = isk ? dk2 : dq2;

    const int lane  = threadIdx.x & 63;
    const int w     = threadIdx.x >> 6;
    const int m0    = blockIdx.x * 128 + w * 32;
    const int chunk = lane >> 4;
    const int cl    = lane & 15;

    floatx4 acc[2][10];
#pragma unroll
    for (int mi = 0; mi < 2; ++mi)
#pragma unroll
        for (int ni = 0; ni < 10; ++ni) acc[mi][ni] = (floatx4)0.0f;

#pragma unroll
    for (int ks = 0; ks < 2; ++ks) {
        short8 a[2];
#pragma unroll
        for (int mi = 0; mi < 2; ++mi)
            a[mi] = *(const short8*)&A[((size_t)h * NPTS + m0 + mi * 16 + cl) * HDIM +
                                       ks * 32 + chunk * 8];
#pragma unroll
        for (int ni = 0; ni < 10; ++ni) {
            int j = ni * 16 + cl;
            short8 b = (short8)0;
            if (j < NL3T) {
                const float* tp = &T[(size_t)(j * NH + h) * HDIM + ks * 32 + chunk * 8];
                float4 f0 = *(const float4*)tp;
                float4 f1 = *(const float4*)(tp + 4);
                b[0] = (short)f2bf(f0.x); b[1] = (short)f2bf(f0.y);
                b[2] = (short)f2bf(f0.z); b[3] = (short)f2bf(f0.w);
                b[4] = (short)f2bf(f1.x); b[5] = (short)f2bf(f1.y);
                b[6] = (short)f2bf(f1.z); b[7] = (short)f2bf(f1.w);
            }
#pragma unroll
            for (int mi = 0; mi < 2; ++mi)
                acc[mi][ni] = __builtin_amdgcn_mfma_f32_16x16x32_bf16(
                    a[mi], b, acc[mi][ni], 0, 0, 0);
        }
    }
#pragma unroll
    for (int mi = 0; mi < 2; ++mi)
#pragma unroll
        for (int ni = 0; ni < 10; ++ni) {
            int j = ni * 16 + cl;
            if (j >= NL3T) continue;
#pragma unroll
            for (int r = 0; r < 4; ++r) {
                int n = m0 + mi * 16 + chunk * 4 + r;
                X[(size_t)n * DSTR + j * 6 + h] = f2bf(acc[mi][ni][r]);
            }
        }
}

// -------------------------------------------------- fused attention per query
// grid NPTS, block 384 = 6 waves; wave h = head h of query blockIdx.x.
// lane = pp*16 + c : pp selects pair-in-group, c selects d-chunk (4 d).
__global__ __launch_bounds__(384) void attn_kernel(
    const unsigned short* __restrict__ qbf, const unsigned short* __restrict__ kh,
    const unsigned short* __restrict__ vh,
    const unsigned int* __restrict__ pairs,
    const unsigned short* __restrict__ dq2, const unsigned short* __restrict__ dk2,
    const unsigned short* __restrict__ Tvbf,
    const int* __restrict__ sortix,
    unsigned short* __restrict__ xb) {
    const int n    = blockIdx.x;
    const int h    = threadIdx.x >> 6;
    const int lane = threadIdx.x & 63;
    const int pp   = lane >> 4, c = lane & 15;

    const ushort4v q4 = *(const ushort4v*)&qbf[((size_t)h * NPTS + n) * HDIM + c * 4];
    const float qx = bf2f(q4.x), qy = bf2f(q4.y), qz = bf2f(q4.z), qw = bf2f(q4.w);

    const unsigned short* dqb = dq2 + (size_t)n * DSTR + h;

    unsigned int pv[4];
#pragma unroll
    for (int g = 0; g < 4; ++g) pv[g] = pairs[n * KNB + g * 4 + pp];

    int keyg[4], j0g[4], j1g[4], j2g[4];
#pragma unroll
    for (int g = 0; g < 4; ++g) {
        keyg[g] = (int)(pv[g] & 0x3FFFu);
        j0g[g]  = (int)((pv[g] >> 14) & 63u) * 18;
        j1g[g]  = (int)((pv[g] >> 20) & 63u) * 18 + 6;
        j2g[g]  = (int)(pv[g] >> 26) * 18 + 12;
    }

    float tab[4];
#pragma unroll
    for (int g = 0; g < 4; ++g) {
        const unsigned short* dkb = dk2 + (size_t)keyg[g] * DSTR + h;
        tab[g] = bf2f(dqb[j0g[g]]) + bf2f(dqb[j1g[g]]) + bf2f(dqb[j2g[g]]) +
                 bf2f(dkb[j0g[g]]) + bf2f(dkb[j1g[g]]) + bf2f(dkb[j2g[g]]);
    }

    float lg[4];
#pragma unroll
    for (int g = 0; g < 4; ++g) {
        const ushort4v k4 =
            *(const ushort4v*)&kh[((size_t)h * NPTS + keyg[g]) * HDIM + c * 4];
        lg[g] = qx * bf2f(k4.x) + qy * bf2f(k4.y) + qz * bf2f(k4.z) + qw * bf2f(k4.w);
    }
#pragma unroll
    for (int m = 1; m <= 8; m <<= 1)
#pragma unroll
        for (int g = 0; g < 4; ++g) lg[g] += __shfl_xor(lg[g], m, 64);
#pragma unroll
    for (int g = 0; g < 4; ++g) lg[g] += tab[g];

    // softmax over 16 pairs (4 in-lane x 4 pp-groups)
    float mx = fmaxf(fmaxf(lg[0], lg[1]), fmaxf(lg[2], lg[3]));
    mx = fmaxf(mx, __shfl_xor(mx, 16, 64));
    mx = fmaxf(mx, __shfl_xor(mx, 32, 64));
    float e[4], s = 0.f;
#pragma unroll
    for (int g = 0; g < 4; ++g) { e[g] = expf(lg[g] - mx); s += e[g]; }
    s += __shfl_xor(s, 16, 64);
    s += __shfl_xor(s, 32, 64);
    const float inv = 1.f / s;

    float xa0 = 0.f, xa1 = 0.f, xa2 = 0.f, xa3 = 0.f;
#pragma unroll
    for (int g = 0; g < 4; ++g) {
        const float wgt = e[g] * inv;
        const ushort4v v4 =
            *(const ushort4v*)&vh[((size_t)h * NPTS + keyg[g]) * HDIM + c * 4];
        const ushort4v t0 = *(const ushort4v*)&Tvbf[(size_t)(j0g[g] + h) * HDIM + c * 4];
        const ushort4v t1 = *(const ushort4v*)&Tvbf[(size_t)(j1g[g] + h) * HDIM + c * 4];
        const ushort4v t2 = *(const ushort4v*)&Tvbf[(size_t)(j2g[g] + h) * HDIM + c * 4];
        xa0 += wgt * (bf2f(v4.x) + bf2f(t0.x) + bf2f(t1.x) + bf2f(t2.x));
        xa1 += wgt * (bf2f(v4.y) + bf2f(t0.y) + bf2f(t1.y) + bf2f(t2.y));
        xa2 += wgt * (bf2f(v4.z) + bf2f(t0.z) + bf2f(t1.z) + bf2f(t2.z));
        xa3 += wgt * (bf2f(v4.w) + bf2f(t0.w) + bf2f(t1.w) + bf2f(t2.w));
    }
#pragma unroll
    for (int m = 16; m <= 32; m <<= 1) {
        xa0 += __shfl_xor(xa0, m, 64);
        xa1 += __shfl_xor(xa1, m, 64);
        xa2 += __shfl_xor(xa2, m, 64);
        xa3 += __shfl_xor(xa3, m, 64);
    }
    if (pp == 0) {
        const int dst = sortix[n]; // unsort
        ushort4v o;
        o.x = f2bf(xa0); o.y = f2bf(xa1); o.z = f2bf(xa2); o.w = f2bf(xa3);
        *(ushort4v*)&xb[(size_t)dst * CDIM + h * HDIM + c * 4] = o;
    }
}

// ---------------------------------------------------------------------------
extern "C" void kernel_launch(void* const* d_in, const int* in_sizes, int n_in,
                              void* d_out, int out_size, void* d_ws,
                              size_t ws_size, hipStream_t stream) {
    const float* feats  = (const float*)d_in[0];
    const float* xyz    = (const float*)d_in[1];
    const int*   index1 = (const int*)d_in[4];
    const int*   sortix = (const int*)d_in[5];
    const float* Wq = (const float*)d_in[6];
    const float* bq = (const float*)d_in[7];
    const float* Wk = (const float*)d_in[8];
    const float* bk = (const float*)d_in[9];
    const float* Wv = (const float*)d_in[10];
    const float* bv = (const float*)d_in[11];
    const float* Wp = (const float*)d_in[12];
    const float* bp = (const float*)d_in[13];
    const float* Tq = (const float*)d_in[14];
    const float* Tk = (const float*)d_in[15];
    const float* Tv = (const float*)d_in[16];
    float* out = (float*)d_out;

    char* ws = (char*)d_ws;
    size_t off = 0;
    auto alloc = [&](size_t bytes) -> void* {
        void* p = ws + off;
        off = (off + bytes + 255) & ~(size_t)255;
        return p;
    };
    unsigned short* featsbf = (unsigned short*)alloc((size_t)NPTS * CDIM * 2);
    unsigned short* Wcat    = (unsigned short*)alloc((size_t)(NQKV + CDIM) * CDIM * 2);
    float*          bcat    = (float*)alloc((NQKV + CDIM) * sizeof(float));
    unsigned short* qbf     = (unsigned short*)alloc((size_t)NH * NPTS * HDIM * 2);
    unsigned short* kh      = (unsigned short*)alloc((size_t)NH * NPTS * HDIM * 2);
    unsigned short* vh      = (unsigned short*)alloc((size_t)NH * NPTS * HDIM * 2);
    unsigned short* dq2     = (unsigned short*)alloc((size_t)NPTS * DSTR * 2);
    unsigned short* dk2     = (unsigned short*)alloc((size_t)NPTS * DSTR * 2);
    unsigned short* xb      = (unsigned short*)alloc((size_t)NPTS * CDIM * 2);
    unsigned short* Tvbf    = (unsigned short*)alloc((size_t)NL3T * NH * HDIM * 2);
    unsigned int*   pairs   = (unsigned int*)alloc((size_t)NPTS * KNB * 4);
    int*            xq      = (int*)alloc((size_t)NPTS * 3 * sizeof(int));
    unsigned int*   minbits = (unsigned int*)alloc(16);

    init_min_kernel<<<1, 64, 0, stream>>>(minbits);
    min_kernel<<<128, 256, 0, stream>>>(xyz, minbits);
    xq_kernel<<<(NPTS + 255) / 256, 256, 0, stream>>>(xyz, sortix, minbits, xq);
    relpack_kernel<<<(NPTS * KNB + 255) / 256, 256, 0, stream>>>(index1, xq, pairs);

    gather_bf16_kernel<<<(NPTS * CDIM / 4 + 255) / 256, 256, 0, stream>>>(
        feats, sortix, featsbf);
    pack_w_kernel<<<((NQKV + CDIM) * CDIM + 255) / 256, 256, 0, stream>>>(
        Wq, Wk, Wv, Wp, bq, bk, bv, bp, Wcat, bcat);
    tvpack_kernel<<<(NL3T * NH * HDIM + 255) / 256, 256, 0, stream>>>(Tv, Tvbf);

    dim3 gq(NPTS / 128, NQKV / 128);
    gemm_fused<<<gq, 256, 0, stream>>>(featsbf, Wcat, bcat, 0, qbf, kh, vh,
                                       (float*)nullptr);

    dim3 gd(NPTS / 128, NH, 2);
    dqdk_kernel<<<gd, 256, 0, stream>>>(qbf, kh, Tq, Tk, dq2, dk2);

    attn_kernel<<<NPTS, 384, 0, stream>>>(qbf, kh, vh, pairs, dq2, dk2, Tvbf,
                                          sortix, xb);

    dim3 gp(NPTS / 128, CDIM / 128);
    gemm_fused<<<gp, 256, 0, stream>>>(xb, Wcat + (size_t)NQKV * CDIM,
                                       bcat + NQKV, 1, qbf, kh, vh, out);
}

// Round 6
// 291.378 us; speedup vs baseline: 1.0019x; 1.0019x over previous
//
#include <hip/hip_runtime.h>
#include <hip/hip_bf16.h>
#include <cstdint>
#include <cstddef>

#define NPTS 16000
#define KNB  16
#define CDIM 384
#define NH   6
#define HDIM 64
#define T2C  49
#define NQKV 1152            // 3*384 fused q,k,v output cols
#define NL3T 147             // 49*3 table rows
#define DSTR 882             // 147*6 : per-point dq/dk row stride (elems)

static constexpr float WIN    = 6.0f;
static constexpr float QUANT  = 0.24f;
static constexpr float QSCALE = 0.125f; // 64^-0.5

typedef __attribute__((ext_vector_type(8))) short short8;
typedef __attribute__((ext_vector_type(4))) float floatx4;
typedef __attribute__((ext_vector_type(4))) unsigned short ushort4v;

__device__ inline unsigned short f2bf(float x) {
    unsigned int u = __float_as_uint(x);
    unsigned int r = (u + 0x7fffu + ((u >> 16) & 1u)) >> 16;
    return (unsigned short)r;
}
__device__ inline float bf2f(unsigned short b) {
    return __uint_as_float(((unsigned int)b) << 16);
}

// ---------------------------------------------------------------- min reduce
__global__ void init_min_kernel(unsigned int* minbits) {
    if (threadIdx.x < 3) minbits[threadIdx.x] = 0x7f800000u; // +inf
}

__global__ void min_kernel(const float* __restrict__ xyz,
                           unsigned int* __restrict__ minbits) {
    float m0 = INFINITY, m1 = INFINITY, m2 = INFINITY;
    for (int i = blockIdx.x * blockDim.x + threadIdx.x; i < NPTS;
         i += gridDim.x * blockDim.x) {
        m0 = fminf(m0, xyz[i * 3 + 0]);
        m1 = fminf(m1, xyz[i * 3 + 1]);
        m2 = fminf(m2, xyz[i * 3 + 2]);
    }
#pragma unroll
    for (int off = 1; off < 64; off <<= 1) {
        m0 = fminf(m0, __shfl_xor(m0, off, 64));
        m1 = fminf(m1, __shfl_xor(m1, off, 64));
        m2 = fminf(m2, __shfl_xor(m2, off, 64));
    }
    if ((threadIdx.x & 63) == 0) {
        atomicMin(&minbits[0], __float_as_uint(m0)); // xyz >= 0
        atomicMin(&minbits[1], __float_as_uint(m1));
        atomicMin(&minbits[2], __float_as_uint(m2));
    }
}

// ------------------------------------------------------------- quantize xyz
__global__ void xq_kernel(const float* __restrict__ xyz,
                          const int* __restrict__ sort_idx,
                          const unsigned int* __restrict__ minbits,
                          int* __restrict__ xq) {
    int n = blockIdx.x * blockDim.x + threadIdx.x;
    if (n >= NPTS) return;
    int orig = sort_idx[n];
#pragma unroll
    for (int t = 0; t < 3; ++t) {
        float mn = __uint_as_float(minbits[t]);
        float v  = xyz[orig * 3 + t] - mn;   // >= 0
        float md = fmodf(v, WIN);            // == np.mod for non-negative
        float q  = floorf(md / QUANT);
        xq[n * 3 + t] = (int)q;
    }
}

// ----------------------------------------------- pack (key, rel0..2) per pair
__global__ void relpack_kernel(const int* __restrict__ idx1,
                               const int* __restrict__ xq,
                               unsigned int* __restrict__ pairs) {
    int m = blockIdx.x * blockDim.x + threadIdx.x;
    if (m >= NPTS * KNB) return;
    int n = m >> 4;
    int key = idx1[m];
    int r0 = xq[n * 3 + 0] - xq[key * 3 + 0] + 24; r0 = min(max(r0, 0), T2C - 1);
    int r1 = xq[n * 3 + 1] - xq[key * 3 + 1] + 24; r1 = min(max(r1, 0), T2C - 1);
    int r2 = xq[n * 3 + 2] - xq[key * 3 + 2] + 24; r2 = min(max(r2, 0), T2C - 1);
    pairs[m] = (unsigned)key | ((unsigned)r0 << 14) | ((unsigned)r1 << 20) |
               ((unsigned)r2 << 26);
}

// ------------------------------------------------- gather+convert feats->bf16
__global__ void gather_bf16_kernel(const float* __restrict__ feats,
                                   const int* __restrict__ sortix,
                                   unsigned short* __restrict__ out) {
    int i = blockIdx.x * blockDim.x + threadIdx.x; // group of 4 elements
    if (i >= NPTS * CDIM / 4) return;
    int n  = i / (CDIM / 4);
    int c4 = (i % (CDIM / 4)) * 4;
    const float4 v = *(const float4*)&feats[(size_t)sortix[n] * CDIM + c4];
    ushort4v o;
    o.x = f2bf(v.x); o.y = f2bf(v.y); o.z = f2bf(v.z); o.w = f2bf(v.w);
    *(ushort4v*)&out[(size_t)n * CDIM + c4] = o;
}

// --------------------------------------------- pack W(q|k|v|p) -> bf16, biases
__global__ void pack_w_kernel(const float* __restrict__ Wq,
                              const float* __restrict__ Wk,
                              const float* __restrict__ Wv,
                              const float* __restrict__ Wp,
                              const float* __restrict__ bq,
                              const float* __restrict__ bk,
                              const float* __restrict__ bv,
                              const float* __restrict__ bp,
                              unsigned short* __restrict__ Wcat,
                              float* __restrict__ bcat) {
    int i = blockIdx.x * blockDim.x + threadIdx.x;
    if (i < NQKV + CDIM)
        bcat[i] = (i < 384) ? bq[i] : (i < 768) ? bk[i - 384]
                : (i < 1152) ? bv[i - 768] : bp[i - 1152];
    if (i >= (NQKV + CDIM) * CDIM) return;
    int j = i / CDIM, k = i % CDIM;
    float v = (j < 384)  ? Wq[j * CDIM + k]
            : (j < 768)  ? Wk[(j - 384) * CDIM + k]
            : (j < 1152) ? Wv[(j - 768) * CDIM + k]
                         : Wp[(j - 1152) * CDIM + k];
    Wcat[i] = f2bf(v);
}

// ----------------------------------------------------------- Tv table -> bf16
__global__ void tvpack_kernel(const float* __restrict__ Tv,
                              unsigned short* __restrict__ Tvbf) {
    int i = blockIdx.x * blockDim.x + threadIdx.x;
    if (i < NL3T * NH * HDIM) Tvbf[i] = f2bf(Tv[i]);
}

// ------------------------------------------------------ fused bf16 MFMA GEMM
// mode 0: A=featsbf [16000x384], W rows 0..1151  -> qbf (bf16,*SCALE), kh, vh
// mode 1: A=xb      [16000x384], W rows 1152..   -> outf (f32 + bias)
__global__ __launch_bounds__(256) void gemm_fused(
    const unsigned short* __restrict__ Abf,
    const unsigned short* __restrict__ Wrows,   // pre-offset
    const float* __restrict__ bias,             // pre-offset
    int mode,
    unsigned short* __restrict__ qb, unsigned short* __restrict__ kb,
    unsigned short* __restrict__ vb, float* __restrict__ outf) {
    __shared__ unsigned short As[128 * 64];
    __shared__ unsigned short Bs[128 * 64];
    const int tid  = threadIdx.x;
    const int lane = tid & 63;
    const int w    = tid >> 6;
    const int wm   = w >> 1, wn = w & 1;
    const int m0   = blockIdx.x * 128;
    const int jn0  = blockIdx.y * 128;

    floatx4 acc[4][4];
#pragma unroll
    for (int i = 0; i < 4; ++i)
#pragma unroll
        for (int j = 0; j < 4; ++j) acc[i][j] = (floatx4)0.0f;

    for (int kt = 0; kt < 6; ++kt) {
        const int k0 = kt * 64;
#pragma unroll
        for (int q = 0; q < 4; ++q) {
            const int s    = w * 4 + q;            // 1KB segment id
            const int row  = s * 8 + (lane >> 3);
            const int col  = (lane & 7) * 8;
            const unsigned short* ga = Abf   + (size_t)(m0  + row) * CDIM + k0 + col;
            const unsigned short* gb = Wrows + (size_t)(jn0 + row) * CDIM + k0 + col;
            __builtin_amdgcn_global_load_lds(
                (const __attribute__((address_space(1))) void*)ga,
                (__attribute__((address_space(3))) void*)&As[s * 512], 16, 0, 0);
            __builtin_amdgcn_global_load_lds(
                (const __attribute__((address_space(1))) void*)gb,
                (__attribute__((address_space(3))) void*)&Bs[s * 512], 16, 0, 0);
        }
        __syncthreads();
#pragma unroll
        for (int ks = 0; ks < 2; ++ks) {
            short8 a[4], b[4];
#pragma unroll
            for (int mi = 0; mi < 4; ++mi) {
                int row = wm * 64 + mi * 16 + (lane & 15);
                a[mi] = *(const short8*)&As[row * 64 + ks * 32 + (lane >> 4) * 8];
            }
#pragma unroll
            for (int ni = 0; ni < 4; ++ni) {
                int jr = wn * 64 + ni * 16 + (lane & 15);
                b[ni] = *(const short8*)&Bs[jr * 64 + ks * 32 + (lane >> 4) * 8];
            }
#pragma unroll
            for (int mi = 0; mi < 4; ++mi)
#pragma unroll
                for (int ni = 0; ni < 4; ++ni)
                    acc[mi][ni] = __builtin_amdgcn_mfma_f32_16x16x32_bf16(
                        a[mi], b[ni], acc[mi][ni], 0, 0, 0);
        }
        __syncthreads();
    }

#pragma unroll
    for (int mi = 0; mi < 4; ++mi)
#pragma unroll
        for (int ni = 0; ni < 4; ++ni) {
            int j = jn0 + wn * 64 + ni * 16 + (lane & 15);
            float bsv = bias[j];
            if (mode == 0) {
                int which = j / CDIM;
                int c = j - which * CDIM;
                int h = c >> 6, d = c & 63;
#pragma unroll
                for (int r = 0; r < 4; ++r) {
                    int n = m0 + wm * 64 + mi * 16 + (lane >> 4) * 4 + r;
                    float val = acc[mi][ni][r] + bsv;
                    size_t o = ((size_t)h * NPTS + n) * HDIM + d;
                    if (which == 0)      qb[o] = f2bf(val * QSCALE);
                    else if (which == 1) kb[o] = f2bf(val);
                    else                 vb[o] = f2bf(val);
                }
            } else {
#pragma unroll
                for (int r = 0; r < 4; ++r) {
                    int n = m0 + wm * 64 + mi * 16 + (lane >> 4) * 4 + r;
                    outf[(size_t)n * CDIM + j] = acc[mi][ni][r] + bsv;
                }
            }
        }
}

// ----------------------------------- dq/dk table-dot GEMM  [N x 64]x[64 x 147]
// X[n][j][h] (bf16) = A[h][n][:] . T[(j*6+h)*64 + :]   for j < 147
__global__ __launch_bounds__(256) void dqdk_kernel(
    const unsigned short* __restrict__ qbf, const unsigned short* __restrict__ kh,
    const float* __restrict__ Tq, const float* __restrict__ Tk,
    unsigned short* __restrict__ dq2, unsigned short* __restrict__ dk2) {
    const int h   = blockIdx.y;
    const bool isk = blockIdx.z != 0;
    const unsigned short* A = isk ? kh : qbf;
    const float* T          = isk ? Tk : Tq;
    unsigned short* X       = isk ? dk2 : dq2;

    const int lane  = threadIdx.x & 63;
    const int w     = threadIdx.x >> 6;
    const int m0    = blockIdx.x * 128 + w * 32;
    const int chunk = lane >> 4;
    const int cl    = lane & 15;

    floatx4 acc[2][10];
#pragma unroll
    for (int mi = 0; mi < 2; ++mi)
#pragma unroll
        for (int ni = 0; ni < 10; ++ni) acc[mi][ni] = (floatx4)0.0f;

#pragma unroll
    for (int ks = 0; ks < 2; ++ks) {
        short8 a[2];
#pragma unroll
        for (int mi = 0; mi < 2; ++mi)
            a[mi] = *(const short8*)&A[((size_t)h * NPTS + m0 + mi * 16 + cl) * HDIM +
                                       ks * 32 + chunk * 8];
#pragma unroll
        for (int ni = 0; ni < 10; ++ni) {
            int j = ni * 16 + cl;
            short8 b = (short8)0;
            if (j < NL3T) {
                const float* tp = &T[(size_t)(j * NH + h) * HDIM + ks * 32 + chunk * 8];
                float4 f0 = *(const float4*)tp;
                float4 f1 = *(const float4*)(tp + 4);
                b[0] = (short)f2bf(f0.x); b[1] = (short)f2bf(f0.y);
                b[2] = (short)f2bf(f0.z); b[3] = (short)f2bf(f0.w);
                b[4] = (short)f2bf(f1.x); b[5] = (short)f2bf(f1.y);
                b[6] = (short)f2bf(f1.z); b[7] = (short)f2bf(f1.w);
            }
#pragma unroll
            for (int mi = 0; mi < 2; ++mi)
                acc[mi][ni] = __builtin_amdgcn_mfma_f32_16x16x32_bf16(
                    a[mi], b, acc[mi][ni], 0, 0, 0);
        }
    }
#pragma unroll
    for (int mi = 0; mi < 2; ++mi)
#pragma unroll
        for (int ni = 0; ni < 10; ++ni) {
            int j = ni * 16 + cl;
            if (j >= NL3T) continue;
#pragma unroll
            for (int r = 0; r < 4; ++r) {
                int n = m0 + mi * 16 + chunk * 4 + r;
                X[(size_t)n * DSTR + j * 6 + h] = f2bf(acc[mi][ni][r]);
            }
        }
}

// -------------------------------------------------- fused attention per query
// grid NPTS, block 384 = 6 waves; wave h = head h of query blockIdx.x.
// lane = pp*16 + c : pp selects pair-in-group, c selects d-chunk (4 d).
__global__ __launch_bounds__(384) void attn_kernel(
    const unsigned short* __restrict__ qbf, const unsigned short* __restrict__ kh,
    const unsigned short* __restrict__ vh,
    const unsigned int* __restrict__ pairs,
    const unsigned short* __restrict__ dq2, const unsigned short* __restrict__ dk2,
    const unsigned short* __restrict__ Tvbf,
    const int* __restrict__ sortix,
    unsigned short* __restrict__ xb) {
    const int n    = blockIdx.x;
    const int h    = threadIdx.x >> 6;
    const int lane = threadIdx.x & 63;
    const int pp   = lane >> 4, c = lane & 15;

    const ushort4v q4 = *(const ushort4v*)&qbf[((size_t)h * NPTS + n) * HDIM + c * 4];
    const float qx = bf2f(q4.x), qy = bf2f(q4.y), qz = bf2f(q4.z), qw = bf2f(q4.w);

    const unsigned short* dqb = dq2 + (size_t)n * DSTR + h;

    unsigned int pv[4];
#pragma unroll
    for (int g = 0; g < 4; ++g) pv[g] = pairs[n * KNB + g * 4 + pp];

    int keyg[4], j0g[4], j1g[4], j2g[4];
#pragma unroll
    for (int g = 0; g < 4; ++g) {
        keyg[g] = (int)(pv[g] & 0x3FFFu);
        j0g[g]  = (int)((pv[g] >> 14) & 63u) * 18;
        j1g[g]  = (int)((pv[g] >> 20) & 63u) * 18 + 6;
        j2g[g]  = (int)(pv[g] >> 26) * 18 + 12;
    }

    float tab[4];
#pragma unroll
    for (int g = 0; g < 4; ++g) {
        const unsigned short* dkb = dk2 + (size_t)keyg[g] * DSTR + h;
        tab[g] = bf2f(dqb[j0g[g]]) + bf2f(dqb[j1g[g]]) + bf2f(dqb[j2g[g]]) +
                 bf2f(dkb[j0g[g]]) + bf2f(dkb[j1g[g]]) + bf2f(dkb[j2g[g]]);
    }

    float lg[4];
#pragma unroll
    for (int g = 0; g < 4; ++g) {
        const ushort4v k4 =
            *(const ushort4v*)&kh[((size_t)h * NPTS + keyg[g]) * HDIM + c * 4];
        lg[g] = qx * bf2f(k4.x) + qy * bf2f(k4.y) + qz * bf2f(k4.z) + qw * bf2f(k4.w);
    }
#pragma unroll
    for (int m = 1; m <= 8; m <<= 1)
#pragma unroll
        for (int g = 0; g < 4; ++g) lg[g] += __shfl_xor(lg[g], m, 64);
#pragma unroll
    for (int g = 0; g < 4; ++g) lg[g] += tab[g];

    // softmax over 16 pairs (4 in-lane x 4 pp-groups)
    float mx = fmaxf(fmaxf(lg[0], lg[1]), fmaxf(lg[2], lg[3]));
    mx = fmaxf(mx, __shfl_xor(mx, 16, 64));
    mx = fmaxf(mx, __shfl_xor(mx, 32, 64));
    float e[4], s = 0.f;
#pragma unroll
    for (int g = 0; g < 4; ++g) { e[g] = expf(lg[g] - mx); s += e[g]; }
    s += __shfl_xor(s, 16, 64);
    s += __shfl_xor(s, 32, 64);
    const float inv = 1.f / s;

    float xa0 = 0.f, xa1 = 0.f, xa2 = 0.f, xa3 = 0.f;
#pragma unroll
    for (int g = 0; g < 4; ++g) {
        const float wgt = e[g] * inv;
        const ushort4v v4 =
            *(const ushort4v*)&vh[((size_t)h * NPTS + keyg[g]) * HDIM + c * 4];
        const ushort4v t0 = *(const ushort4v*)&Tvbf[(size_t)(j0g[g] + h) * HDIM + c * 4];
        const ushort4v t1 = *(const ushort4v*)&Tvbf[(size_t)(j1g[g] + h) * HDIM + c * 4];
        const ushort4v t2 = *(const ushort4v*)&Tvbf[(size_t)(j2g[g] + h) * HDIM + c * 4];
        xa0 += wgt * (bf2f(v4.x) + bf2f(t0.x) + bf2f(t1.x) + bf2f(t2.x));
        xa1 += wgt * (bf2f(v4.y) + bf2f(t0.y) + bf2f(t1.y) + bf2f(t2.y));
        xa2 += wgt * (bf2f(v4.z) + bf2f(t0.z) + bf2f(t1.z) + bf2f(t2.z));
        xa3 += wgt * (bf2f(v4.w) + bf2f(t0.w) + bf2f(t1.w) + bf2f(t2.w));
    }
#pragma unroll
    for (int m = 16; m <= 32; m <<= 1) {
        xa0 += __shfl_xor(xa0, m, 64);
        xa1 += __shfl_xor(xa1, m, 64);
        xa2 += __shfl_xor(xa2, m, 64);
        xa3 += __shfl_xor(xa3, m, 64);
    }
    if (pp == 0) {
        const int dst = sortix[n]; // unsort
        ushort4v o;
        o.x = f2bf(xa0); o.y = f2bf(xa1); o.z = f2bf(xa2); o.w = f2bf(xa3);
        *(ushort4v*)&xb[(size_t)dst * CDIM + h * HDIM + c * 4] = o;
    }
}

// ---------------------------------------------------------------------------
extern "C" void kernel_launch(void* const* d_in, const int* in_sizes, int n_in,
                              void* d_out, int out_size, void* d_ws,
                              size_t ws_size, hipStream_t stream) {
    const float* feats  = (const float*)d_in[0];
    const float* xyz    = (const float*)d_in[1];
    const int*   index1 = (const int*)d_in[4];
    const int*   sortix = (const int*)d_in[5];
    const float* Wq = (const float*)d_in[6];
    const float* bq = (const float*)d_in[7];
    const float* Wk = (const float*)d_in[8];
    const float* bk = (const float*)d_in[9];
    const float* Wv = (const float*)d_in[10];
    const float* bv = (const float*)d_in[11];
    const float* Wp = (const float*)d_in[12];
    const float* bp = (const float*)d_in[13];
    const float* Tq = (const float*)d_in[14];
    const float* Tk = (const float*)d_in[15];
    const float* Tv = (const float*)d_in[16];
    float* out = (float*)d_out;

    char* ws = (char*)d_ws;
    size_t off = 0;
    auto alloc = [&](size_t bytes) -> void* {
        void* p = ws + off;
        off = (off + bytes + 255) & ~(size_t)255;
        return p;
    };
    unsigned short* featsbf = (unsigned short*)alloc((size_t)NPTS * CDIM * 2);
    unsigned short* Wcat    = (unsigned short*)alloc((size_t)(NQKV + CDIM) * CDIM * 2);
    float*          bcat    = (float*)alloc((NQKV + CDIM) * sizeof(float));
    unsigned short* qbf     = (unsigned short*)alloc((size_t)NH * NPTS * HDIM * 2);
    unsigned short* kh      = (unsigned short*)alloc((size_t)NH * NPTS * HDIM * 2);
    unsigned short* vh      = (unsigned short*)alloc((size_t)NH * NPTS * HDIM * 2);
    unsigned short* dq2     = (unsigned short*)alloc((size_t)NPTS * DSTR * 2);
    unsigned short* dk2     = (unsigned short*)alloc((size_t)NPTS * DSTR * 2);
    unsigned short* xb      = (unsigned short*)alloc((size_t)NPTS * CDIM * 2);
    unsigned short* Tvbf    = (unsigned short*)alloc((size_t)NL3T * NH * HDIM * 2);
    unsigned int*   pairs   = (unsigned int*)alloc((size_t)NPTS * KNB * 4);
    int*            xq      = (int*)alloc((size_t)NPTS * 3 * sizeof(int));
    unsigned int*   minbits = (unsigned int*)alloc(16);

    init_min_kernel<<<1, 64, 0, stream>>>(minbits);
    min_kernel<<<128, 256, 0, stream>>>(xyz, minbits);
    xq_kernel<<<(NPTS + 255) / 256, 256, 0, stream>>>(xyz, sortix, minbits, xq);
    relpack_kernel<<<(NPTS * KNB + 255) / 256, 256, 0, stream>>>(index1, xq, pairs);

    gather_bf16_kernel<<<(NPTS * CDIM / 4 + 255) / 256, 256, 0, stream>>>(
        feats, sortix, featsbf);
    pack_w_kernel<<<((NQKV + CDIM) * CDIM + 255) / 256, 256, 0, stream>>>(
        Wq, Wk, Wv, Wp, bq, bk, bv, bp, Wcat, bcat);
    tvpack_kernel<<<(NL3T * NH * HDIM + 255) / 256, 256, 0, stream>>>(Tv, Tvbf);

    dim3 gq(NPTS / 128, NQKV / 128);
    gemm_fused<<<gq, 256, 0, stream>>>(featsbf, Wcat, bcat, 0, qbf, kh, vh,
                                       (float*)nullptr);

    dim3 gd(NPTS / 128, NH, 2);
    dqdk_kernel<<<gd, 256, 0, stream>>>(qbf, kh, Tq, Tk, dq2, dk2);

    attn_kernel<<<NPTS, 384, 0, stream>>>(qbf, kh, vh, pairs, dq2, dk2, Tvbf,
                                          sortix, xb);

    dim3 gp(NPTS / 128, CDIM / 128);
    gemm_fused<<<gp, 256, 0, stream>>>(xb, Wcat + (size_t)NQKV * CDIM,
                                       bcat + NQKV, 1, qbf, kh, vh, out);
}

// Round 7
// 237.587 us; speedup vs baseline: 1.2287x; 1.2264x over previous
//
#include <hip/hip_runtime.h>
#include <hip/hip_bf16.h>
#include <cstdint>
#include <cstddef>

#define NPTS 16000
#define KNB  16
#define CDIM 384
#define NH   6
#define HDIM 64
#define T2C  49
#define NL3T 147             // 49*3 table rows
#define DQPAD 896            // padded dq/dk column-region width (7 x 128)
#define NXC  2944            // 384*3 + 896*2 unified GEMM output cols
// column regions in QX: [0,384)=q  [384,768)=k  [768,1152)=v
//                       [1152,2048)=dq (882 used)  [2048,2944)=dk (882 used)

static constexpr float WIN    = 6.0f;
static constexpr float QUANT  = 0.24f;
static constexpr float QSCALE = 0.125f; // 64^-0.5

typedef __attribute__((ext_vector_type(8))) short short8;
typedef __attribute__((ext_vector_type(4))) float floatx4;
typedef __attribute__((ext_vector_type(4))) unsigned short ushort4v;

__device__ inline unsigned short f2bf(float x) {
    unsigned int u = __float_as_uint(x);
    unsigned int r = (u + 0x7fffu + ((u >> 16) & 1u)) >> 16;
    return (unsigned short)r;
}
__device__ inline float bf2f(unsigned short b) {
    return __uint_as_float(((unsigned int)b) << 16);
}

// ---------------------------------------------------------------- min reduce
__global__ void init_min_kernel(unsigned int* minbits) {
    if (threadIdx.x < 3) minbits[threadIdx.x] = 0x7f800000u; // +inf
}

__global__ void min_kernel(const float* __restrict__ xyz,
                           unsigned int* __restrict__ minbits) {
    float m0 = INFINITY, m1 = INFINITY, m2 = INFINITY;
    for (int i = blockIdx.x * blockDim.x + threadIdx.x; i < NPTS;
         i += gridDim.x * blockDim.x) {
        m0 = fminf(m0, xyz[i * 3 + 0]);
        m1 = fminf(m1, xyz[i * 3 + 1]);
        m2 = fminf(m2, xyz[i * 3 + 2]);
    }
#pragma unroll
    for (int off = 1; off < 64; off <<= 1) {
        m0 = fminf(m0, __shfl_xor(m0, off, 64));
        m1 = fminf(m1, __shfl_xor(m1, off, 64));
        m2 = fminf(m2, __shfl_xor(m2, off, 64));
    }
    if ((threadIdx.x & 63) == 0) {
        atomicMin(&minbits[0], __float_as_uint(m0)); // xyz >= 0
        atomicMin(&minbits[1], __float_as_uint(m1));
        atomicMin(&minbits[2], __float_as_uint(m2));
    }
}

// ------------------------------------------------------------- quantize xyz
__global__ void xq_kernel(const float* __restrict__ xyz,
                          const int* __restrict__ sort_idx,
                          const unsigned int* __restrict__ minbits,
                          int* __restrict__ xq) {
    int n = blockIdx.x * blockDim.x + threadIdx.x;
    if (n >= NPTS) return;
    int orig = sort_idx[n];
#pragma unroll
    for (int t = 0; t < 3; ++t) {
        float mn = __uint_as_float(minbits[t]);
        float v  = xyz[orig * 3 + t] - mn;   // >= 0
        float md = fmodf(v, WIN);            // == np.mod for non-negative
        float q  = floorf(md / QUANT);
        xq[n * 3 + t] = (int)q;
    }
}

// ----------------------------------------------- pack (key, rel0..2) per pair
__global__ void relpack_kernel(const int* __restrict__ idx1,
                               const int* __restrict__ xq,
                               unsigned int* __restrict__ pairs) {
    int m = blockIdx.x * blockDim.x + threadIdx.x;
    if (m >= NPTS * KNB) return;
    int n = m >> 4;
    int key = idx1[m];
    int r0 = xq[n * 3 + 0] - xq[key * 3 + 0] + 24; r0 = min(max(r0, 0), T2C - 1);
    int r1 = xq[n * 3 + 1] - xq[key * 3 + 1] + 24; r1 = min(max(r1, 0), T2C - 1);
    int r2 = xq[n * 3 + 2] - xq[key * 3 + 2] + 24; r2 = min(max(r2, 0), T2C - 1);
    pairs[m] = (unsigned)key | ((unsigned)r0 << 14) | ((unsigned)r1 << 20) |
               ((unsigned)r2 << 26);
}

// ------------------------ fused prep: feats gather->bf16, weight packs, biases
#define G0 (NPTS * CDIM / 4)       // featsbf float4 groups
#define G1 (3 * CDIM * CDIM)       // Wall rows 0..1151
#define G2 (CDIM * CDIM)           // Wpbf
#define G3 (NL3T * NH * HDIM)      // Tvbf
#define G4 (3 * CDIM)              // bfull qkv part
#define G5 (CDIM)                  // bproj
__global__ void prep_kernel(const float* __restrict__ feats,
                            const int* __restrict__ sortix,
                            const float* __restrict__ Wq,
                            const float* __restrict__ Wk,
                            const float* __restrict__ Wv,
                            const float* __restrict__ Wp,
                            const float* __restrict__ bq,
                            const float* __restrict__ bk,
                            const float* __restrict__ bv,
                            const float* __restrict__ bp,
                            const float* __restrict__ Tv,
                            unsigned short* __restrict__ featsbf,
                            unsigned short* __restrict__ Wall,
                            unsigned short* __restrict__ Wpbf,
                            unsigned short* __restrict__ Tvbf,
                            float* __restrict__ bfull,
                            float* __restrict__ bproj) {
    int i = blockIdx.x * blockDim.x + threadIdx.x;
    if (i < G0) {
        int n  = i / (CDIM / 4);
        int c4 = (i % (CDIM / 4)) * 4;
        const float4 v = *(const float4*)&feats[(size_t)sortix[n] * CDIM + c4];
        ushort4v o;
        o.x = f2bf(v.x); o.y = f2bf(v.y); o.z = f2bf(v.z); o.w = f2bf(v.w);
        *(ushort4v*)&featsbf[(size_t)n * CDIM + c4] = o;
        return;
    }
    i -= G0;
    if (i < G1) {
        int j = i / CDIM, k = i % CDIM;
        float v = (j < 384) ? Wq[j * CDIM + k]
                : (j < 768) ? Wk[(j - 384) * CDIM + k]
                            : Wv[(j - 768) * CDIM + k];
        Wall[i] = f2bf(v);
        return;
    }
    i -= G1;
    if (i < G2) { Wpbf[i] = f2bf(Wp[i]); return; }
    i -= G2;
    if (i < G3) { Tvbf[i] = f2bf(Tv[i]); return; }
    i -= G3;
    if (i < G4) {
        bfull[i] = (i < 384) ? bq[i] : (i < 768) ? bk[i - 384] : bv[i - 768];
        return;
    }
    i -= G4;
    if (i < G5) { bproj[i] = bp[i]; }
}

// ---------------- effective rel-pos weights: Weff[(j*6+h), c] = s * T[j,h,:].W_h[:,c]
// blockIdx.x = rr (0..895), blockIdx.y: 0 = q-path (scale=QSCALE), 1 = k-path
__global__ __launch_bounds__(384) void weff_kernel(
    const float* __restrict__ Wq, const float* __restrict__ Wk,
    const float* __restrict__ bq, const float* __restrict__ bk,
    const float* __restrict__ Tq, const float* __restrict__ Tk,
    unsigned short* __restrict__ Wall, float* __restrict__ bfull) {
    const int rr   = blockIdx.x;
    const bool isk = blockIdx.y != 0;
    const int base = isk ? 2048 : 1152;
    const float sc = isk ? 1.0f : QSCALE;
    const float* W = isk ? Wk : Wq;
    const float* bv = isk ? bk : bq;
    const float* T = isk ? Tk : Tq;
    const int c = threadIdx.x;

    if (rr >= NL3T * NH) {   // pad rows: zero
        Wall[(size_t)(base + rr) * CDIM + c] = 0;
        if (c == 0) bfull[base + rr] = 0.0f;
        return;
    }
    const int h = rr % NH;

    __shared__ float Trow[HDIM];
    if (c < HDIM) Trow[c] = T[(size_t)rr * HDIM + c];
    __syncthreads();

    float acc = 0.0f;
#pragma unroll
    for (int d = 0; d < HDIM; ++d)
        acc += Trow[d] * W[(size_t)(h * HDIM + d) * CDIM + c];
    Wall[(size_t)(base + rr) * CDIM + c] = f2bf(acc * sc);

    if (c == 0) {
        float bacc = 0.0f;
#pragma unroll
        for (int d = 0; d < HDIM; ++d) bacc += Trow[d] * bv[h * HDIM + d];
        bfull[base + rr] = bacc * sc;
    }
}

// ------------------------------------------------------ fused bf16 MFMA GEMM
// mode 0: A=featsbf, W=Wall [NXC x 384] -> QX bf16 [NPTS][NXC] (bias, q-scale)
// mode 1: A=xb,      W=Wpbf [384 x 384] -> out f32 [NPTS][384] (bias)
// Operands are SWAPPED in the mfma call so each acc fragment holds 4
// consecutive output COLUMNS of one row -> packed 8B/16B stores.
__global__ __launch_bounds__(256) void gemm_big(
    const unsigned short* __restrict__ Abf,
    const unsigned short* __restrict__ Wmat,
    const float* __restrict__ bias,
    int mode, int nxout,
    unsigned short* __restrict__ QX, float* __restrict__ outf) {
    __shared__ unsigned short As[128 * 64];
    __shared__ unsigned short Bs[128 * 64];
    const int tid  = threadIdx.x;
    const int lane = tid & 63;
    const int w    = tid >> 6;
    const int wm   = w >> 1, wn = w & 1;
    const int jn0  = blockIdx.x * 128;   // column tile (fast dim: W reuse in L2)
    const int m0   = blockIdx.y * 128;

    floatx4 acc[4][4];
#pragma unroll
    for (int i = 0; i < 4; ++i)
#pragma unroll
        for (int j = 0; j < 4; ++j) acc[i][j] = (floatx4)0.0f;

    for (int kt = 0; kt < 6; ++kt) {
        const int k0 = kt * 64;
#pragma unroll
        for (int q = 0; q < 4; ++q) {
            const int s    = w * 4 + q;            // 1KB segment id
            const int row  = s * 8 + (lane >> 3);
            const int col  = (lane & 7) * 8;
            const unsigned short* ga = Abf  + (size_t)(m0  + row) * CDIM + k0 + col;
            const unsigned short* gb = Wmat + (size_t)(jn0 + row) * CDIM + k0 + col;
            __builtin_amdgcn_global_load_lds(
                (const __attribute__((address_space(1))) void*)ga,
                (__attribute__((address_space(3))) void*)&As[s * 512], 16, 0, 0);
            __builtin_amdgcn_global_load_lds(
                (const __attribute__((address_space(1))) void*)gb,
                (__attribute__((address_space(3))) void*)&Bs[s * 512], 16, 0, 0);
        }
        __syncthreads();
#pragma unroll
        for (int ks = 0; ks < 2; ++ks) {
            short8 a[4], b[4];
#pragma unroll
            for (int mi = 0; mi < 4; ++mi) {
                int row = wm * 64 + mi * 16 + (lane & 15);
                a[mi] = *(const short8*)&As[row * 64 + ks * 32 + (lane >> 4) * 8];
            }
#pragma unroll
            for (int ni = 0; ni < 4; ++ni) {
                int jr = wn * 64 + ni * 16 + (lane & 15);
                b[ni] = *(const short8*)&Bs[jr * 64 + ks * 32 + (lane >> 4) * 8];
            }
            // swapped operands: D[row=jj, col=n]
#pragma unroll
            for (int mi = 0; mi < 4; ++mi)
#pragma unroll
                for (int ni = 0; ni < 4; ++ni)
                    acc[mi][ni] = __builtin_amdgcn_mfma_f32_16x16x32_bf16(
                        b[ni], a[mi], acc[mi][ni], 0, 0, 0);
        }
        __syncthreads();
    }

#pragma unroll
    for (int mi = 0; mi < 4; ++mi) {
        const int n = m0 + wm * 64 + mi * 16 + (lane & 15);
#pragma unroll
        for (int ni = 0; ni < 4; ++ni) {
            const int jjb = jn0 + wn * 64 + ni * 16 + (lane >> 4) * 4;
            const float4 b4 = *(const float4*)&bias[jjb];
            if (mode == 0) {
                const float scl = (jjb < 384) ? QSCALE : 1.0f;
                ushort4v o;
                o.x = f2bf((acc[mi][ni][0] + b4.x) * scl);
                o.y = f2bf((acc[mi][ni][1] + b4.y) * scl);
                o.z = f2bf((acc[mi][ni][2] + b4.z) * scl);
                o.w = f2bf((acc[mi][ni][3] + b4.w) * scl);
                *(ushort4v*)&QX[(size_t)n * nxout + jjb] = o;
            } else {
                float4 o;
                o.x = acc[mi][ni][0] + b4.x;
                o.y = acc[mi][ni][1] + b4.y;
                o.z = acc[mi][ni][2] + b4.z;
                o.w = acc[mi][ni][3] + b4.w;
                *(float4*)&outf[(size_t)n * nxout + jjb] = o;
            }
        }
    }
}

// -------------------------------------------------- fused attention per query
// grid NPTS, block 384 = 6 waves; wave h = head h of query blockIdx.x.
// lane = pp*16 + c : pp selects pair-in-group, c selects d-chunk (4 d).
__global__ __launch_bounds__(384) void attn_kernel(
    const unsigned short* __restrict__ QX,
    const unsigned int* __restrict__ pairs,
    const unsigned short* __restrict__ Tvbf,
    const int* __restrict__ sortix,
    unsigned short* __restrict__ xb) {
    const int n    = blockIdx.x;
    const int h    = threadIdx.x >> 6;
    const int lane = threadIdx.x & 63;
    const int pp   = lane >> 4, c = lane & 15;

    const unsigned short* qrow = QX + (size_t)n * NXC;
    const ushort4v q4 = *(const ushort4v*)&qrow[h * HDIM + c * 4];
    const float qx = bf2f(q4.x), qy = bf2f(q4.y), qz = bf2f(q4.z), qw = bf2f(q4.w);

    unsigned int pv[4];
#pragma unroll
    for (int g = 0; g < 4; ++g) pv[g] = pairs[n * KNB + g * 4 + pp];

    const unsigned short* krow[4];
    int j0g[4], j1g[4], j2g[4];
#pragma unroll
    for (int g = 0; g < 4; ++g) {
        krow[g] = QX + (size_t)(pv[g] & 0x3FFFu) * NXC;
        j0g[g]  = (int)((pv[g] >> 14) & 63u) * 18;
        j1g[g]  = (int)((pv[g] >> 20) & 63u) * 18 + 6;
        j2g[g]  = (int)(pv[g] >> 26) * 18 + 12;
    }

    float tab[4];
#pragma unroll
    for (int g = 0; g < 4; ++g) {
        tab[g] = bf2f(qrow[1152 + j0g[g] + h]) + bf2f(qrow[1152 + j1g[g] + h]) +
                 bf2f(qrow[1152 + j2g[g] + h]) +
                 bf2f(krow[g][2048 + j0g[g] + h]) + bf2f(krow[g][2048 + j1g[g] + h]) +
                 bf2f(krow[g][2048 + j2g[g] + h]);
    }

    float lg[4];
#pragma unroll
    for (int g = 0; g < 4; ++g) {
        const ushort4v k4 = *(const ushort4v*)&krow[g][384 + h * HDIM + c * 4];
        lg[g] = qx * bf2f(k4.x) + qy * bf2f(k4.y) + qz * bf2f(k4.z) + qw * bf2f(k4.w);
    }
#pragma unroll
    for (int m = 1; m <= 8; m <<= 1)
#pragma unroll
        for (int g = 0; g < 4; ++g) lg[g] += __shfl_xor(lg[g], m, 64);
#pragma unroll
    for (int g = 0; g < 4; ++g) lg[g] += tab[g];

    // softmax over 16 pairs (4 in-lane x 4 pp-groups)
    float mx = fmaxf(fmaxf(lg[0], lg[1]), fmaxf(lg[2], lg[3]));
    mx = fmaxf(mx, __shfl_xor(mx, 16, 64));
    mx = fmaxf(mx, __shfl_xor(mx, 32, 64));
    float e[4], s = 0.f;
#pragma unroll
    for (int g = 0; g < 4; ++g) { e[g] = expf(lg[g] - mx); s += e[g]; }
    s += __shfl_xor(s, 16, 64);
    s += __shfl_xor(s, 32, 64);
    const float inv = 1.f / s;

    float xa0 = 0.f, xa1 = 0.f, xa2 = 0.f, xa3 = 0.f;
#pragma unroll
    for (int g = 0; g < 4; ++g) {
        const float wgt = e[g] * inv;
        const ushort4v v4 = *(const ushort4v*)&krow[g][768 + h * HDIM + c * 4];
        const ushort4v t0 = *(const ushort4v*)&Tvbf[(size_t)(j0g[g] + h) * HDIM + c * 4];
        const ushort4v t1 = *(const ushort4v*)&Tvbf[(size_t)(j1g[g] + h) * HDIM + c * 4];
        const ushort4v t2 = *(const ushort4v*)&Tvbf[(size_t)(j2g[g] + h) * HDIM + c * 4];
        xa0 += wgt * (bf2f(v4.x) + bf2f(t0.x) + bf2f(t1.x) + bf2f(t2.x));
        xa1 += wgt * (bf2f(v4.y) + bf2f(t0.y) + bf2f(t1.y) + bf2f(t2.y));
        xa2 += wgt * (bf2f(v4.z) + bf2f(t0.z) + bf2f(t1.z) + bf2f(t2.z));
        xa3 += wgt * (bf2f(v4.w) + bf2f(t0.w) + bf2f(t1.w) + bf2f(t2.w));
    }
#pragma unroll
    for (int m = 16; m <= 32; m <<= 1) {
        xa0 += __shfl_xor(xa0, m, 64);
        xa1 += __shfl_xor(xa1, m, 64);
        xa2 += __shfl_xor(xa2, m, 64);
        xa3 += __shfl_xor(xa3, m, 64);
    }
    if (pp == 0) {
        const int dst = sortix[n]; // unsort
        ushort4v o;
        o.x = f2bf(xa0); o.y = f2bf(xa1); o.z = f2bf(xa2); o.w = f2bf(xa3);
        *(ushort4v*)&xb[(size_t)dst * CDIM + h * HDIM + c * 4] = o;
    }
}

// ---------------------------------------------------------------------------
extern "C" void kernel_launch(void* const* d_in, const int* in_sizes, int n_in,
                              void* d_out, int out_size, void* d_ws,
                              size_t ws_size, hipStream_t stream) {
    const float* feats  = (const float*)d_in[0];
    const float* xyz    = (const float*)d_in[1];
    const int*   index1 = (const int*)d_in[4];
    const int*   sortix = (const int*)d_in[5];
    const float* Wq = (const float*)d_in[6];
    const float* bq = (const float*)d_in[7];
    const float* Wk = (const float*)d_in[8];
    const float* bk = (const float*)d_in[9];
    const float* Wv = (const float*)d_in[10];
    const float* bv = (const float*)d_in[11];
    const float* Wp = (const float*)d_in[12];
    const float* bp = (const float*)d_in[13];
    const float* Tq = (const float*)d_in[14];
    const float* Tk = (const float*)d_in[15];
    const float* Tv = (const float*)d_in[16];
    float* out = (float*)d_out;

    char* ws = (char*)d_ws;
    size_t off = 0;
    auto alloc = [&](size_t bytes) -> void* {
        void* p = ws + off;
        off = (off + bytes + 255) & ~(size_t)255;
        return p;
    };
    unsigned short* featsbf = (unsigned short*)alloc((size_t)NPTS * CDIM * 2); // reused as xb
    unsigned short* Wall    = (unsigned short*)alloc((size_t)NXC * CDIM * 2);
    unsigned short* Wpbf    = (unsigned short*)alloc((size_t)CDIM * CDIM * 2);
    unsigned short* Tvbf    = (unsigned short*)alloc((size_t)NL3T * NH * HDIM * 2);
    float*          bfull   = (float*)alloc((size_t)NXC * sizeof(float));
    float*          bproj   = (float*)alloc((size_t)CDIM * sizeof(float));
    unsigned short* QX      = (unsigned short*)alloc((size_t)NPTS * NXC * 2);
    unsigned int*   pairs   = (unsigned int*)alloc((size_t)NPTS * KNB * 4);
    int*            xq      = (int*)alloc((size_t)NPTS * 3 * sizeof(int));
    unsigned int*   minbits = (unsigned int*)alloc(16);
    unsigned short* xb      = featsbf; // featsbf dead after gemm0

    init_min_kernel<<<1, 64, 0, stream>>>(minbits);
    min_kernel<<<128, 256, 0, stream>>>(xyz, minbits);
    xq_kernel<<<(NPTS + 255) / 256, 256, 0, stream>>>(xyz, sortix, minbits, xq);
    relpack_kernel<<<(NPTS * KNB + 255) / 256, 256, 0, stream>>>(index1, xq, pairs);

    const int prep_total = G0 + G1 + G2 + G3 + G4 + G5;
    prep_kernel<<<(prep_total + 255) / 256, 256, 0, stream>>>(
        feats, sortix, Wq, Wk, Wv, Wp, bq, bk, bv, bp, Tv,
        featsbf, Wall, Wpbf, Tvbf, bfull, bproj);

    dim3 gw(DQPAD, 2);
    weff_kernel<<<gw, 384, 0, stream>>>(Wq, Wk, bq, bk, Tq, Tk, Wall, bfull);

    dim3 g0(NXC / 128, NPTS / 128);
    gemm_big<<<g0, 256, 0, stream>>>(featsbf, Wall, bfull, 0, NXC, QX,
                                     (float*)nullptr);

    attn_kernel<<<NPTS, 384, 0, stream>>>(QX, pairs, Tvbf, sortix, xb);

    dim3 g1(CDIM / 128, NPTS / 128);
    gemm_big<<<g1, 256, 0, stream>>>(xb, Wpbf, bproj, 1, CDIM,
                                     (unsigned short*)nullptr, out);
}